// Round 17
// baseline (208.008 us; speedup 1.0000x reference)
//
#include <hip/hip_runtime.h>
#include <hip/hip_bf16.h>

typedef __attribute__((ext_vector_type(8))) short bf16x8;
typedef __attribute__((ext_vector_type(4))) float f32x4;
typedef __attribute__((ext_vector_type(16))) float f32x16;

#define N_NODES 8192
#define D_IN    256
#define D_OUT   128
#define LOG2E   1.44269504088896f

__device__ __forceinline__ unsigned short bf16_rne(float f) {
  unsigned int u = __float_as_uint(f);
  u += 0x7fffu + ((u >> 16) & 1u);
  return (unsigned short)(u >> 16);
}
__device__ __forceinline__ float bf16_to_f(unsigned short s) {
  return __uint_as_float(((unsigned int)s) << 16);
}
__device__ __forceinline__ unsigned int pack_bf16x2(float lo, float hi) {
  __hip_bfloat162 b2 = __float22bfloat162_rn(make_float2(lo, hi));
  union { __hip_bfloat162 b; unsigned int u; } cv;
  cv.b = b2;
  return cv.u;
}

// ------------- k0b: split + transpose W -> W_hiT, W_loT [128][256] -------------
__global__ __launch_bounds__(256) void k_split_w(const float* __restrict__ W,
                                                 unsigned short* __restrict__ whiT,
                                                 unsigned short* __restrict__ wloT) {
  int c = blockIdx.x;
  int k = threadIdx.x;
  float v = W[k * D_OUT + c];
  unsigned short h = bf16_rne(v);
  unsigned short l = bf16_rne(v - bf16_to_f(h));
  whiT[c * D_IN + k] = h;
  wloT[c * D_IN + k] = l;
}

// ---- k1: h = x @ W (x converted hi/lo in-register) + src/dst dots + B-panel pack ----
__global__ __launch_bounds__(256) void k_h_gemm(const float* __restrict__ x,
                                                const unsigned short* __restrict__ whiT,
                                                const unsigned short* __restrict__ wloT,
                                                const float* __restrict__ a_src,
                                                const float* __restrict__ a_dst,
                                                float* __restrict__ srcv,
                                                float* __restrict__ dstv,
                                                unsigned short* __restrict__ phi) {
  __shared__ float h_s[32][128];
  const int t = threadIdx.x, l = t & 63, wv = t >> 6;
  const int i0 = blockIdx.x * 32;
  const int m = wv >> 1, nh = wv & 1;
  const int frow = l & 15, kq = l >> 4;
  const size_t arow = (size_t)(i0 + m * 16 + frow);
  const float* px = x + arow * D_IN + kq * 8;
  f32x4 acc[4];
#pragma unroll
  for (int nf = 0; nf < 4; ++nf) acc[nf] = (f32x4){0.f, 0.f, 0.f, 0.f};
#pragma unroll
  for (int kk = 0; kk < 8; ++kk) {
    const int k0 = kk * 32;
    float4 xv0 = *(const float4*)(px + k0);
    float4 xv1 = *(const float4*)(px + k0 + 4);
    float xv[8] = {xv0.x, xv0.y, xv0.z, xv0.w, xv1.x, xv1.y, xv1.z, xv1.w};
    union { bf16x8 v; unsigned short s[8]; } ah, al;
#pragma unroll
    for (int e = 0; e < 8; ++e) {
      ah.s[e] = bf16_rne(xv[e]);
      al.s[e] = bf16_rne(xv[e] - bf16_to_f(ah.s[e]));
    }
#pragma unroll
    for (int nf = 0; nf < 4; ++nf) {
      const int col = nh * 64 + nf * 16 + frow;
      bf16x8 bh = *(const bf16x8*)(whiT + (size_t)col * D_IN + k0 + kq * 8);
      bf16x8 bl = *(const bf16x8*)(wloT + (size_t)col * D_IN + k0 + kq * 8);
      acc[nf] = __builtin_amdgcn_mfma_f32_16x16x32_bf16(ah.v, bh, acc[nf], 0, 0, 0);
      acc[nf] = __builtin_amdgcn_mfma_f32_16x16x32_bf16(al.v, bh, acc[nf], 0, 0, 0);
      acc[nf] = __builtin_amdgcn_mfma_f32_16x16x32_bf16(ah.v, bl, acc[nf], 0, 0, 0);
    }
  }
#pragma unroll
  for (int nf = 0; nf < 4; ++nf)
#pragma unroll
    for (int r = 0; r < 4; ++r)
      h_s[m * 16 + kq * 4 + r][nh * 64 + nf * 16 + frow] = acc[nf][r];
  __syncthreads();

  if (t < 32) {
    float s = 0.f, d = 0.f;
#pragma unroll
    for (int c = 0; c < D_OUT; ++c) {
      float v = h_s[t][c];
      s += v * a_src[c];
      d += v * a_dst[c];
    }
    srcv[i0 + t] = s * LOG2E;
    dstv[i0 + t] = d * LOG2E;
  }

  {
    const int b = t >> 7, ct = (t >> 5) & 3, lw = t & 31;
    const size_t kg = (size_t)(i0 / 16 + b);
#pragma unroll
    for (int half = 0; half < 2; ++half) {
      const int lane = lw + 32 * half;
      unsigned int hw[4];
#pragma unroll
      for (int p = 0; p < 4; ++p) {
        float v0 = h_s[b * 16 + half * 8 + 2 * p][ct * 32 + lw];
        float v1 = h_s[b * 16 + half * 8 + 2 * p + 1][ct * 32 + lw];
        hw[p] = (unsigned int)bf16_rne(v0) | ((unsigned int)bf16_rne(v1) << 16);
      }
      const size_t off = ((kg * 4 + ct) * 64 + lane) * 8;
      *(uint4*)(phi + off) = make_uint4(hw[0], hw[1], hw[2], hw[3]);
    }
  }
}

// ---------------- k3: FUSED stream+convert+aggregate (v17: w-dedup, 4-ct waves) ----------------
// grid 512 = 256 row-tiles x 2 j-halves; 512 threads = 8 waves, js = wv (0..7).
// Each wave owns ONE 32-j slice per 256-j chunk and ALL FOUR 32-col ct tiles:
// w computed exactly ONCE per (row, j) per block (v14 computed it twice, once per
// ch group) -> chip-wide w-compute VALU halves. 8 MFMA + 8 B-frags per chunk-iter.
// acc = 4 x f32x16 (64 VGPR); B single-buffered (w-compute overlaps load latency).
// adj producer, mask layout, dstv staging identical to v14 (proven).
__global__ __launch_bounds__(512) __attribute__((amdgpu_waves_per_eu(4, 4)))
void k_gat(const int* __restrict__ adj,
           const float* __restrict__ srcv,
           const float* __restrict__ dstv,
           const unsigned short* __restrict__ phi,
           float* __restrict__ pnum,
           float* __restrict__ prsum) {
  __shared__ unsigned long long mbuf[2][4][33];  // 2.1 KB double-buffered mask chunk
  __shared__ float dstv_s[4096];                 // 16 KB: this block's j-half
  __shared__ float red[4][1024];                 // 16 KB js-reduction buffer (one acc-set)
  __shared__ float rsl[8][32];

  const int t = threadIdx.x, l = t & 63, wv = t >> 6;
  const int js = wv;                             // 0..7: j-slice AND reduction id
  const int bid = blockIdx.x;
  const int tile = bid & 255, jh = bid >> 8;
  const int i0 = tile * 32;
  const int r32 = l & 31, kh = l >> 5;

  ((float4*)dstv_s)[t] = ((const float4*)(dstv + jh * 4096))[t];
  ((float4*)dstv_s)[t + 512] = ((const float4*)(dstv + jh * 4096))[t + 512];
  const float s2 = srcv[i0 + r32];

  // conv: wave wv owns rows 4wv..4wv+3; step s: row 4wv+(s>>2), word s&3, lane bit l
  const int* abase = adj + (size_t)(i0 + 4 * wv) * N_NODES + jh * 4096 + l;

  int cva[16];
  // prologue: chunk 0 -> ballot mbuf[0]; then cva = chunk 1 loads
#pragma unroll
  for (int s = 0; s < 16; ++s)
    cva[s] = __builtin_nontemporal_load(abase + (s >> 2) * N_NODES + (s & 3) * 64);
#pragma unroll
  for (int s = 0; s < 16; ++s) {
    unsigned long long b = __ballot(cva[s] > 0);
    if (l == 0) mbuf[0][s & 3][4 * wv + (s >> 2)] = b;
  }
#pragma unroll
  for (int s = 0; s < 16; ++s)
    cva[s] = __builtin_nontemporal_load(abase + (s >> 2) * N_NODES + 256 + (s & 3) * 64);

  // B panel base at kstep kst0 = jh*256 + js*2, ct 0.
  // Frag (chunk c, ks, ct) at pb0 + c*32768 + ks*2048 + ct*512   [ushort units]
  const int kst0 = jh * 256 + js * 2;
  const unsigned short* pb0 = phi + ((size_t)(kst0 * 4) * 64 + l) * 8;

  const int wrd = js >> 1;                       // mask word within chunk
  const int shl = (js & 1) * 32 + kh * 8;

  f32x16 acc0, acc1, acc2, acc3;
#pragma unroll
  for (int q = 0; q < 16; ++q) { acc0[q] = 0.f; acc1[q] = 0.f; acc2[q] = 0.f; acc3[q] = 0.f; }
  float rs = 0.f;

  __syncthreads();  // mbuf[0] + dstv_s ready

  for (int c = 0; c < 16; ++c) {
    // ---- B frags for this chunk (issue all 8 early; w-compute below covers latency)
    const unsigned short* pc = pb0 + c * 32768;
    bf16x8 b0 = *(const bf16x8*)(pc);
    bf16x8 b1 = *(const bf16x8*)(pc + 512);
    bf16x8 b2 = *(const bf16x8*)(pc + 1024);
    bf16x8 b3 = *(const bf16x8*)(pc + 1536);
    bf16x8 b4 = *(const bf16x8*)(pc + 2048);
    bf16x8 b5 = *(const bf16x8*)(pc + 2048 + 512);
    bf16x8 b6 = *(const bf16x8*)(pc + 2048 + 1024);
    bf16x8 b7 = *(const bf16x8*)(pc + 2048 + 1536);

    const unsigned long long mw = mbuf[c & 1][wrd][r32];
    const int jl = c * 256 + js * 32 + kh * 8;
    const unsigned int u0 = (unsigned int)(mw >> shl) & 0xFFu;
    const unsigned int u1 = (unsigned int)(mw >> (shl + 16)) & 0xFFu;

    // ---- ks = 0: w once, 4 MFMA (all ct) ----
    {
      f32x4 dva = *(const f32x4*)&dstv_s[jl];
      f32x4 dvb = *(const f32x4*)&dstv_s[jl + 4];
      float w[8];
#pragma unroll
      for (int e = 0; e < 4; ++e) {
        float e0 = s2 + dva[e]; e0 = fmaxf(e0, 0.2f * e0);
        float e1 = s2 + dvb[e]; e1 = fmaxf(e1, 0.2f * e1);
        w[e]     = ((u0 >> e) & 1u)       ? __builtin_amdgcn_exp2f(e0) : 0.f;
        w[4 + e] = ((u0 >> (4 + e)) & 1u) ? __builtin_amdgcn_exp2f(e1) : 0.f;
      }
      rs += ((w[0] + w[1]) + (w[2] + w[3])) + ((w[4] + w[5]) + (w[6] + w[7]));
      union { bf16x8 v; unsigned int u4[4]; } af;
#pragma unroll
      for (int p = 0; p < 4; ++p)
        af.u4[p] = pack_bf16x2(w[2 * p], w[2 * p + 1]);
      acc0 = __builtin_amdgcn_mfma_f32_32x32x16_bf16(af.v, b0, acc0, 0, 0, 0);
      acc1 = __builtin_amdgcn_mfma_f32_32x32x16_bf16(af.v, b1, acc1, 0, 0, 0);
      acc2 = __builtin_amdgcn_mfma_f32_32x32x16_bf16(af.v, b2, acc2, 0, 0, 0);
      acc3 = __builtin_amdgcn_mfma_f32_32x32x16_bf16(af.v, b3, acc3, 0, 0, 0);
    }
    // ---- ks = 1 ----
    {
      f32x4 dva = *(const f32x4*)&dstv_s[jl + 16];
      f32x4 dvb = *(const f32x4*)&dstv_s[jl + 20];
      float w[8];
#pragma unroll
      for (int e = 0; e < 4; ++e) {
        float e0 = s2 + dva[e]; e0 = fmaxf(e0, 0.2f * e0);
        float e1 = s2 + dvb[e]; e1 = fmaxf(e1, 0.2f * e1);
        w[e]     = ((u1 >> e) & 1u)       ? __builtin_amdgcn_exp2f(e0) : 0.f;
        w[4 + e] = ((u1 >> (4 + e)) & 1u) ? __builtin_amdgcn_exp2f(e1) : 0.f;
      }
      rs += ((w[0] + w[1]) + (w[2] + w[3])) + ((w[4] + w[5]) + (w[6] + w[7]));
      union { bf16x8 v; unsigned int u4[4]; } af;
#pragma unroll
      for (int p = 0; p < 4; ++p)
        af.u4[p] = pack_bf16x2(w[2 * p], w[2 * p + 1]);
      acc0 = __builtin_amdgcn_mfma_f32_32x32x16_bf16(af.v, b4, acc0, 0, 0, 0);
      acc1 = __builtin_amdgcn_mfma_f32_32x32x16_bf16(af.v, b5, acc1, 0, 0, 0);
      acc2 = __builtin_amdgcn_mfma_f32_32x32x16_bf16(af.v, b6, acc2, 0, 0, 0);
      acc3 = __builtin_amdgcn_mfma_f32_32x32x16_bf16(af.v, b7, acc3, 0, 0, 0);
    }

    // end of chunk: ballot cva (chunk c+1 data, loaded a full chunk ago) -> mbuf,
    // then reissue cva for chunk c+2 (r9's proven schedule).
    if (c < 15) {
#pragma unroll
      for (int s = 0; s < 16; ++s) {
        unsigned long long b = __ballot(cva[s] > 0);
        if (l == 0) mbuf[(c + 1) & 1][s & 3][4 * wv + (s >> 2)] = b;
      }
      if (c < 14) {
        const int nb = (c + 2) * 256;
#pragma unroll
        for (int s = 0; s < 16; ++s)
          cva[s] = __builtin_nontemporal_load(abase + (s >> 2) * N_NODES + nb + (s & 3) * 64);
      }
    }
    __syncthreads();
  }

  // rowsum: each wave covered its j-slices exactly once
  rs += __shfl_xor(rs, 32);
  if (kh == 0) rsl[js][r32] = rs;

  // js-reduction of numerators: 7 serial rounds through the 16 KB buffer
#pragma unroll
  for (int q = 1; q < 8; ++q) {
    if (js == q) {
#pragma unroll
      for (int reg = 0; reg < 16; ++reg) {
        red[0][reg * 64 + l] = acc0[reg];
        red[1][reg * 64 + l] = acc1[reg];
        red[2][reg * 64 + l] = acc2[reg];
        red[3][reg * 64 + l] = acc3[reg];
      }
    }
    __syncthreads();
    if (js == 0) {
#pragma unroll
      for (int reg = 0; reg < 16; ++reg) {
        acc0[reg] += red[0][reg * 64 + l];
        acc1[reg] += red[1][reg * 64 + l];
        acc2[reg] += red[2][reg * 64 + l];
        acc3[reg] += red[3][reg * 64 + l];
      }
    }
    __syncthreads();
  }

  if (js == 0) {
    float* pn = pnum + (size_t)bid * 4096;
#pragma unroll
    for (int reg = 0; reg < 16; ++reg) {
      const int row = (reg & 3) + 8 * (reg >> 2) + 4 * kh;
      pn[row * 128 + r32]      = acc0[reg];
      pn[row * 128 + 32 + r32] = acc1[reg];
      pn[row * 128 + 64 + r32] = acc2[reg];
      pn[row * 128 + 96 + r32] = acc3[reg];
    }
    if (kh == 0)
      prsum[bid * 32 + r32] = (((rsl[0][r32] + rsl[1][r32]) + (rsl[2][r32] + rsl[3][r32])) +
                               ((rsl[4][r32] + rsl[5][r32]) + (rsl[6][r32] + rsl[7][r32])));
  }
}

// ---------------- k4: merge j-halves, divide by rowsum ----------------
__global__ __launch_bounds__(1024) void k_comb(const float* __restrict__ pnum,
                                               const float* __restrict__ prsum,
                                               float* __restrict__ out) {
  const int tile = blockIdx.x, t = threadIdx.x;
  const float4 a = ((const float4*)(pnum + (size_t)tile * 4096))[t];
  const float4 b = ((const float4*)(pnum + (size_t)(256 + tile) * 4096))[t];
  const int row = t >> 5;
  const float r = prsum[tile * 32 + row] + prsum[(256 + tile) * 32 + row];
  float4 o;
  o.x = (a.x + b.x) / r;
  o.y = (a.y + b.y) / r;
  o.z = (a.z + b.z) / r;
  o.w = (a.w + b.w) / r;
  ((float4*)(out + (size_t)tile * 4096))[t] = o;
}

extern "C" void kernel_launch(void* const* d_in, const int* in_sizes, int n_in,
                              void* d_out, int out_size, void* d_ws, size_t ws_size,
                              hipStream_t stream) {
  const float* x     = (const float*)d_in[0];
  const int*   adj   = (const int*)d_in[1];
  const float* W     = (const float*)d_in[2];
  const float* a_src = (const float*)d_in[3];
  const float* a_dst = (const float*)d_in[4];
  float* out = (float*)d_out;

  char* ws = (char*)d_ws;
  float*          pnum = (float*)(ws);                                        // 8 MB
  float*          prsum= (float*)(ws + (8 << 20));                            // 64 KB
  unsigned short* whiT = (unsigned short*)(ws + (8 << 20) + (64 << 10));      // 64 KB
  unsigned short* wloT = (unsigned short*)(ws + (8 << 20) + (128 << 10));     // 64 KB
  unsigned short* phi  = (unsigned short*)(ws + (8 << 20) + (192 << 10));     // 2 MB
  float*          srcv = (float*)(ws + (10 << 20) + (192 << 10));             // 32 KB
  float*          dstv = (float*)(ws + (10 << 20) + (224 << 10));             // 32 KB

  k_split_w<<<dim3(128), dim3(256), 0, stream>>>(W, whiT, wloT);
  k_h_gemm<<<dim3(256), dim3(256), 0, stream>>>(x, whiT, wloT,
                                                a_src, a_dst, srcv, dstv, phi);
  k_gat<<<dim3(512), dim3(512), 0, stream>>>(adj, srcv, dstv, phi, pnum, prsum);
  k_comb<<<dim3(256), dim3(1024), 0, stream>>>(pnum, prsum, out);
}

// Round 18
// 98.049 us; speedup vs baseline: 2.1215x; 2.1215x over previous
//
#include <hip/hip_runtime.h>
#include <hip/hip_bf16.h>

typedef __attribute__((ext_vector_type(8))) short bf16x8;
typedef __attribute__((ext_vector_type(4))) float f32x4;
typedef __attribute__((ext_vector_type(16))) float f32x16;

#define N_NODES 8192
#define D_IN    256
#define D_OUT   128
#define LOG2E   1.44269504088896f

__device__ __forceinline__ unsigned short bf16_rne(float f) {
  unsigned int u = __float_as_uint(f);
  u += 0x7fffu + ((u >> 16) & 1u);
  return (unsigned short)(u >> 16);
}
__device__ __forceinline__ float bf16_to_f(unsigned short s) {
  return __uint_as_float(((unsigned int)s) << 16);
}
__device__ __forceinline__ unsigned int pack_bf16x2(float lo, float hi) {
  __hip_bfloat162 b2 = __float22bfloat162_rn(make_float2(lo, hi));
  union { __hip_bfloat162 b; unsigned int u; } cv;
  cv.b = b2;
  return cv.u;
}

// ------------- k0b: split + transpose W -> W_hiT, W_loT [128][256] -------------
__global__ __launch_bounds__(256) void k_split_w(const float* __restrict__ W,
                                                 unsigned short* __restrict__ whiT,
                                                 unsigned short* __restrict__ wloT) {
  int c = blockIdx.x;
  int k = threadIdx.x;
  float v = W[k * D_OUT + c];
  unsigned short h = bf16_rne(v);
  unsigned short l = bf16_rne(v - bf16_to_f(h));
  whiT[c * D_IN + k] = h;
  wloT[c * D_IN + k] = l;
}

// ---- k1: h = x @ W (x converted hi/lo in-register) + src/dst dots + B-panel pack ----
__global__ __launch_bounds__(256) void k_h_gemm(const float* __restrict__ x,
                                                const unsigned short* __restrict__ whiT,
                                                const unsigned short* __restrict__ wloT,
                                                const float* __restrict__ a_src,
                                                const float* __restrict__ a_dst,
                                                float* __restrict__ srcv,
                                                float* __restrict__ dstv,
                                                unsigned short* __restrict__ phi) {
  __shared__ float h_s[32][128];
  const int t = threadIdx.x, l = t & 63, wv = t >> 6;
  const int i0 = blockIdx.x * 32;
  const int m = wv >> 1, nh = wv & 1;
  const int frow = l & 15, kq = l >> 4;
  const size_t arow = (size_t)(i0 + m * 16 + frow);
  const float* px = x + arow * D_IN + kq * 8;
  f32x4 acc[4];
#pragma unroll
  for (int nf = 0; nf < 4; ++nf) acc[nf] = (f32x4){0.f, 0.f, 0.f, 0.f};
#pragma unroll
  for (int kk = 0; kk < 8; ++kk) {
    const int k0 = kk * 32;
    float4 xv0 = *(const float4*)(px + k0);
    float4 xv1 = *(const float4*)(px + k0 + 4);
    float xv[8] = {xv0.x, xv0.y, xv0.z, xv0.w, xv1.x, xv1.y, xv1.z, xv1.w};
    union { bf16x8 v; unsigned short s[8]; } ah, al;
#pragma unroll
    for (int e = 0; e < 8; ++e) {
      ah.s[e] = bf16_rne(xv[e]);
      al.s[e] = bf16_rne(xv[e] - bf16_to_f(ah.s[e]));
    }
#pragma unroll
    for (int nf = 0; nf < 4; ++nf) {
      const int col = nh * 64 + nf * 16 + frow;
      bf16x8 bh = *(const bf16x8*)(whiT + (size_t)col * D_IN + k0 + kq * 8);
      bf16x8 bl = *(const bf16x8*)(wloT + (size_t)col * D_IN + k0 + kq * 8);
      acc[nf] = __builtin_amdgcn_mfma_f32_16x16x32_bf16(ah.v, bh, acc[nf], 0, 0, 0);
      acc[nf] = __builtin_amdgcn_mfma_f32_16x16x32_bf16(al.v, bh, acc[nf], 0, 0, 0);
      acc[nf] = __builtin_amdgcn_mfma_f32_16x16x32_bf16(ah.v, bl, acc[nf], 0, 0, 0);
    }
  }
#pragma unroll
  for (int nf = 0; nf < 4; ++nf)
#pragma unroll
    for (int r = 0; r < 4; ++r)
      h_s[m * 16 + kq * 4 + r][nh * 64 + nf * 16 + frow] = acc[nf][r];
  __syncthreads();

  if (t < 32) {
    float s = 0.f, d = 0.f;
#pragma unroll
    for (int c = 0; c < D_OUT; ++c) {
      float v = h_s[t][c];
      s += v * a_src[c];
      d += v * a_dst[c];
    }
    srcv[i0 + t] = s * LOG2E;
    dstv[i0 + t] = d * LOG2E;
  }

  {
    const int b = t >> 7, ct = (t >> 5) & 3, lw = t & 31;
    const size_t kg = (size_t)(i0 / 16 + b);
#pragma unroll
    for (int half = 0; half < 2; ++half) {
      const int lane = lw + 32 * half;
      unsigned int hw[4];
#pragma unroll
      for (int p = 0; p < 4; ++p) {
        float v0 = h_s[b * 16 + half * 8 + 2 * p][ct * 32 + lw];
        float v1 = h_s[b * 16 + half * 8 + 2 * p + 1][ct * 32 + lw];
        hw[p] = (unsigned int)bf16_rne(v0) | ((unsigned int)bf16_rne(v1) << 16);
      }
      const size_t off = ((kg * 4 + ct) * 64 + lane) * 8;
      *(uint4*)(phi + off) = make_uint4(hw[0], hw[1], hw[2], hw[3]);
    }
  }
}

// ---------------- k3: FUSED stream+convert+aggregate (v18 = v14 + launch_bounds(512,2)) ----------------
// grid 512 = 256 row-tiles x 2 j-halves; 512 threads = 8 waves: ch = wv>>2, js = wv&3.
// (512,2): min 2 waves/EU -> 256-VGPR budget. r4/r5 showed the compiler picks 68-92
// under this bound (it does NOT blindly chase 8 waves/EU), so v14's ~110-reg working
// set (acc 32 + B-dbuf 32 + cva 16 + temps) can finally live entirely in registers.
// (r12/r17 PMC: at >=4 waves/EU the heuristic pins VGPR=64 and spills the pipeline.)
__global__ __launch_bounds__(512, 2)
void k_gat(const int* __restrict__ adj,
           const float* __restrict__ srcv,
           const float* __restrict__ dstv,
           const unsigned short* __restrict__ phi,
           float* __restrict__ pnum,
           float* __restrict__ prsum) {
  __shared__ unsigned long long mbuf[2][4][33];  // 2.1 KB double-buffered mask chunk
  __shared__ float dstv_s[4096];                 // 16 KB: this block's j-half
  __shared__ float red[2][2048];                 // 16 KB js-reduction buffer
  __shared__ float rsl[4][32];

  const int t = threadIdx.x, l = t & 63, wv = t >> 6;
  const int ch = wv >> 2, js = wv & 3;
  const int bid = blockIdx.x;
  const int tile = bid & 255, jh = bid >> 8;
  const int i0 = tile * 32;
  const int r32 = l & 31, kh = l >> 5;

  ((float4*)dstv_s)[t] = ((const float4*)(dstv + jh * 4096))[t];
  ((float4*)dstv_s)[t + 512] = ((const float4*)(dstv + jh * 4096))[t + 512];
  const float s2 = srcv[i0 + r32];

  // conv: wave wv owns rows 4wv..4wv+3; step s: row 4wv+(s>>2), word s&3, lane bit l
  const int* abase = adj + (size_t)(i0 + 4 * wv) * N_NODES + jh * 4096 + l;

  int cva[16];
  // prologue: chunk 0 -> ballot mbuf[0]; then cva = chunk 1 loads
#pragma unroll
  for (int s = 0; s < 16; ++s)
    cva[s] = __builtin_nontemporal_load(abase + (s >> 2) * N_NODES + (s & 3) * 64);
#pragma unroll
  for (int s = 0; s < 16; ++s) {
    unsigned long long b = __ballot(cva[s] > 0);
    if (l == 0) mbuf[0][s & 3][4 * wv + (s >> 2)] = b;
  }
#pragma unroll
  for (int s = 0; s < 16; ++s)
    cva[s] = __builtin_nontemporal_load(abase + (s >> 2) * N_NODES + 256 + (s & 3) * 64);

  // B panel base; strides (ushorts): chunk 32768, it 16384, ks 2048, ct 512
  const int kst0 = jh * 256 + js * 2;
  const unsigned short* pb0 = phi + ((size_t)(kst0 * 4 + ch * 2) * 64 + l) * 8;
  bf16x8 b00A = *(const bf16x8*)(pb0);
  bf16x8 b01A = *(const bf16x8*)(pb0 + 512);
  bf16x8 b10A = *(const bf16x8*)(pb0 + 2048);
  bf16x8 b11A = *(const bf16x8*)(pb0 + 2048 + 512);

  const int shl = (js & 1) * 32 + kh * 8;
  const int w0 = js >> 1;

  f32x16 acc0, acc1;
#pragma unroll
  for (int q = 0; q < 16; ++q) { acc0[q] = 0.f; acc1[q] = 0.f; }
  float rs = 0.f;

  __syncthreads();  // mbuf[0] + dstv_s ready

  for (int c = 0; c < 16; ++c) {
#pragma unroll
    for (int it = 0; it < 2; ++it) {
      // prefetch next iteration's B frags (named regs)
      int nc = c, nit = it + 1;
      if (nit == 2) { nit = 0; nc = (c < 15) ? c + 1 : 15; }
      const unsigned short* pan = pb0 + nc * 32768 + nit * 16384;
      bf16x8 b00B = *(const bf16x8*)(pan);
      bf16x8 b01B = *(const bf16x8*)(pan + 512);
      bf16x8 b10B = *(const bf16x8*)(pan + 2048);
      bf16x8 b11B = *(const bf16x8*)(pan + 2048 + 512);
      __builtin_amdgcn_sched_barrier(0);

      const unsigned long long mw = mbuf[c & 1][it * 2 + w0][r32];
      const int jl = c * 256 + it * 128 + js * 32 + kh * 8;
      const unsigned int u0 = (unsigned int)(mw >> shl) & 0xFFu;
      const unsigned int u1 = (unsigned int)(mw >> (shl + 16)) & 0xFFu;

#pragma unroll
      for (int ks = 0; ks < 2; ++ks) {
        f32x4 dva = *(const f32x4*)&dstv_s[jl + ks * 16];
        f32x4 dvb = *(const f32x4*)&dstv_s[jl + ks * 16 + 4];
        const unsigned int u = ks ? u1 : u0;
        float w[8];
#pragma unroll
        for (int e = 0; e < 4; ++e) {
          float e0 = s2 + dva[e]; e0 = fmaxf(e0, 0.2f * e0);
          float e1 = s2 + dvb[e]; e1 = fmaxf(e1, 0.2f * e1);
          w[e]     = ((u >> e) & 1u)       ? __builtin_amdgcn_exp2f(e0) : 0.f;
          w[4 + e] = ((u >> (4 + e)) & 1u) ? __builtin_amdgcn_exp2f(e1) : 0.f;
        }
        if (ch == 0)
          rs += ((w[0] + w[1]) + (w[2] + w[3])) + ((w[4] + w[5]) + (w[6] + w[7]));
        union { bf16x8 v; unsigned int u4[4]; } af;
#pragma unroll
        for (int p = 0; p < 4; ++p)
          af.u4[p] = pack_bf16x2(w[2 * p], w[2 * p + 1]);

        if (ks == 0) {
          acc0 = __builtin_amdgcn_mfma_f32_32x32x16_bf16(af.v, b00A, acc0, 0, 0, 0);
          acc1 = __builtin_amdgcn_mfma_f32_32x32x16_bf16(af.v, b01A, acc1, 0, 0, 0);
        } else {
          acc0 = __builtin_amdgcn_mfma_f32_32x32x16_bf16(af.v, b10A, acc0, 0, 0, 0);
          acc1 = __builtin_amdgcn_mfma_f32_32x32x16_bf16(af.v, b11A, acc1, 0, 0, 0);
        }
      }
      b00A = b00B; b01A = b01B; b10A = b10B; b11A = b11B;
    }

    // end of chunk: ballot cva (chunk c+1 data, loaded a full chunk ago) -> mbuf,
    // then reissue cva for chunk c+2 (r9's proven schedule).
    if (c < 15) {
#pragma unroll
      for (int s = 0; s < 16; ++s) {
        unsigned long long b = __ballot(cva[s] > 0);
        if (l == 0) mbuf[(c + 1) & 1][s & 3][4 * wv + (s >> 2)] = b;
      }
      if (c < 14) {
        const int nb = (c + 2) * 256;
#pragma unroll
        for (int s = 0; s < 16; ++s)
          cva[s] = __builtin_nontemporal_load(abase + (s >> 2) * N_NODES + nb + (s & 3) * 64);
      }
    }
    __syncthreads();
  }

  // rowsum across kh halves; stash per js
  rs += __shfl_xor(rs, 32);
  if (ch == 0 && kh == 0) rsl[js][r32] = rs;

  // js-reduction of numerators: 3 serial rounds through 16 KB buffer
#pragma unroll
  for (int q = 1; q < 4; ++q) {
    if (js == q) {
#pragma unroll
      for (int reg = 0; reg < 16; ++reg) {
        red[ch][reg * 64 + l] = acc0[reg];
        red[ch][1024 + reg * 64 + l] = acc1[reg];
      }
    }
    __syncthreads();
    if (js == 0) {
#pragma unroll
      for (int reg = 0; reg < 16; ++reg) {
        acc0[reg] += red[ch][reg * 64 + l];
        acc1[reg] += red[ch][1024 + reg * 64 + l];
      }
    }
    __syncthreads();
  }

  if (js == 0) {
    float* pn = pnum + (size_t)bid * 4096;
#pragma unroll
    for (int reg = 0; reg < 16; ++reg) {
      const int row = (reg & 3) + 8 * (reg >> 2) + 4 * kh;
      pn[row * 128 + ch * 64 + r32] = acc0[reg];
      pn[row * 128 + ch * 64 + 32 + r32] = acc1[reg];
    }
    if (ch == 0 && kh == 0)
      prsum[bid * 32 + r32] = (rsl[0][r32] + rsl[1][r32]) + (rsl[2][r32] + rsl[3][r32]);
  }
}

// ---------------- k4: merge j-halves, divide by rowsum ----------------
__global__ __launch_bounds__(1024) void k_comb(const float* __restrict__ pnum,
                                               const float* __restrict__ prsum,
                                               float* __restrict__ out) {
  const int tile = blockIdx.x, t = threadIdx.x;
  const float4 a = ((const float4*)(pnum + (size_t)tile * 4096))[t];
  const float4 b = ((const float4*)(pnum + (size_t)(256 + tile) * 4096))[t];
  const int row = t >> 5;
  const float r = prsum[tile * 32 + row] + prsum[(256 + tile) * 32 + row];
  float4 o;
  o.x = (a.x + b.x) / r;
  o.y = (a.y + b.y) / r;
  o.z = (a.z + b.z) / r;
  o.w = (a.w + b.w) / r;
  ((float4*)(out + (size_t)tile * 4096))[t] = o;
}

extern "C" void kernel_launch(void* const* d_in, const int* in_sizes, int n_in,
                              void* d_out, int out_size, void* d_ws, size_t ws_size,
                              hipStream_t stream) {
  const float* x     = (const float*)d_in[0];
  const int*   adj   = (const int*)d_in[1];
  const float* W     = (const float*)d_in[2];
  const float* a_src = (const float*)d_in[3];
  const float* a_dst = (const float*)d_in[4];
  float* out = (float*)d_out;

  char* ws = (char*)d_ws;
  float*          pnum = (float*)(ws);                                        // 8 MB
  float*          prsum= (float*)(ws + (8 << 20));                            // 64 KB
  unsigned short* whiT = (unsigned short*)(ws + (8 << 20) + (64 << 10));      // 64 KB
  unsigned short* wloT = (unsigned short*)(ws + (8 << 20) + (128 << 10));     // 64 KB
  unsigned short* phi  = (unsigned short*)(ws + (8 << 20) + (192 << 10));     // 2 MB
  float*          srcv = (float*)(ws + (10 << 20) + (192 << 10));             // 32 KB
  float*          dstv = (float*)(ws + (10 << 20) + (224 << 10));             // 32 KB

  k_split_w<<<dim3(128), dim3(256), 0, stream>>>(W, whiT, wloT);
  k_h_gemm<<<dim3(256), dim3(256), 0, stream>>>(x, whiT, wloT,
                                                a_src, a_dst, srcv, dstv, phi);
  k_gat<<<dim3(512), dim3(512), 0, stream>>>(adj, srcv, dstv, phi, pnum, prsum);
  k_comb<<<dim3(256), dim3(1024), 0, stream>>>(pnum, prsum, out);
}